// Round 7
// baseline (587.282 us; speedup 1.0000x reference)
//
#include <hip/hip_runtime.h>
#include <stdint.h>

typedef __bf16 bf16;
typedef bf16 bf16x8 __attribute__((ext_vector_type(8)));
typedef float f32x4 __attribute__((ext_vector_type(4)));

#define B_  4
#define L_  4096
#define DM  1024
#define DS  256
#define DH  4096
#define BL  16384   // B_*L_
#define CL  64      // scan chunk length
#define NC  64      // chunks per sequence

__device__ __forceinline__ float bfbits(uint32_t lo16) {
  union { uint32_t u; float f; } v; v.u = lo16 << 16; return v.f;
}

__device__ __forceinline__ void async16(const bf16* g, bf16* l) {
  __builtin_amdgcn_global_load_lds(
      (const __attribute__((address_space(1))) uint32_t*)g,
      (__attribute__((address_space(3))) uint32_t*)l, 16, 0, 0);
}

#define MEMFENCE()  asm volatile("" ::: "memory")
#define LGKM0()     asm volatile("s_waitcnt lgkmcnt(0)" ::: "memory")
#define MFMA16(a, b, c) __builtin_amdgcn_mfma_f32_16x16x32_bf16((a), (b), (c), 0, 0, 0)
#define SGB(mask, n) __builtin_amdgcn_sched_group_barrier((mask), (n), 0)
// masks: MFMA=0x8, VMEM|VMEM_READ=0x30, DS_READ=0x100

// ---------------- Fused prep: conv_x | prep_y | prep_bu | W1^T | W2^T | phaseA
__global__ void prep_fused(const float4* __restrict__ x, bf16* __restrict__ XS,
                           const float* __restrict__ C_re, const float* __restrict__ C_im,
                           const float* __restrict__ D_mat, bf16* __restrict__ WBy,
                           const float* __restrict__ B_re, const float* __restrict__ B_im,
                           const float* __restrict__ nu_log, const float* __restrict__ th_log,
                           bf16* __restrict__ WBbu,
                           const float* __restrict__ W1, bf16* __restrict__ WB1,
                           const float* __restrict__ W2, bf16* __restrict__ WB2,
                           float* __restrict__ scal) {
  __shared__ float tile[32][33];
  int bid = blockIdx.x, tid = threadIdx.x;
  if (bid < 16384) {                       // conv_x: x f32 -> XS[.,512..1536) bf16
    size_t i = (size_t)bid * 256 + tid;
    size_t t = i >> 8;
    int d4 = (int)(i & 255);
    float4 v = x[i];
    bf16* o = XS + t * 1536 + 512 + (size_t)d4 * 4;
    o[0] = (bf16)v.x; o[1] = (bf16)v.y; o[2] = (bf16)v.z; o[3] = (bf16)v.w;
  } else if (bid < 22528) {                // prep_y: [C_re|-C_im|D] 1024x1536
    size_t i = (size_t)(bid - 16384) * 256 + tid;
    int m = (int)(i / 1536), c = (int)(i % 1536);
    float v;
    if (c < 256)       v = C_re[m * 256 + c];
    else if (c < 512)  v = -C_im[m * 256 + (c - 256)];
    else               v = D_mat[m * 1024 + (c - 512)];
    WBy[i] = (bf16)v;
  } else if (bid < 24576) {                // prep_bu: gamma*B interleaved 512x1024
    size_t i = (size_t)(bid - 22528) * 256 + tid;
    int row = (int)(i >> 10), col = (int)(i & 1023);
    int n = row >> 1;
    float mod = __expf(-__expf(nu_log[n]));
    float g = sqrtf(fmaxf(1.0f - mod * mod, 0.0f));
    const float* src = (row & 1) ? B_im : B_re;
    WBbu[i] = (bf16)(g * src[n * 1024 + col]);
  } else if (bid < 32768) {                // transposes (f32 -> bf16)
    const float* in; bf16* out; int R, C, bx, by;
    if (bid < 28672) { int t = bid - 24576; in = W1; out = WB1; R = 1024; C = 4096; bx = t & 127; by = t >> 7; }
    else             { int t = bid - 28672; in = W2; out = WB2; R = 4096; C = 1024; bx = t & 31;  by = t >> 5; }
    int c0 = bx * 32, r0 = by * 32, tx = tid & 31, ty = tid >> 5;
    for (int i = 0; i < 32; i += 8)
      tile[ty + i][tx] = in[(size_t)(r0 + ty + i) * C + c0 + tx];
    __syncthreads();
    for (int i = 0; i < 32; i += 8)
      out[(size_t)(c0 + ty + i) * R + r0 + tx] = (bf16)tile[tx][ty + i];
  } else {                                 // phaseA (1 block)
    int n = tid;
    float nu = __expf(nu_log[n]);
    float th = __expf(th_log[n]);
    float mod = __expf(-nu);
    float lr = mod * cosf(th);
    float li = mod * sinf(th);
    float g = sqrtf(fmaxf(1.0f - mod * mod, 0.0f));
    float pr = 1.f, pi = 0.f;
    for (int i = 0; i < CL; i++) {
      float nr = pr * lr - pi * li;
      float ni = pr * li + pi * lr;
      pr = nr; pi = ni;
    }
    scal[n] = lr; scal[256 + n] = li;
    scal[512 + n] = pr; scal[768 + n] = pi;
    scal[1024 + n] = g;
  }
}

// Shared epilogue. EPI: 0 = bf16 store, 1 = gelu->bf16, 2 = xres + sig*acc (f32)
template <int EPI>
__device__ __forceinline__ void epi_store(void* C, int ldc, size_t row, size_t col,
                                          float v, float sig, const float* xres) {
  size_t off = row * (size_t)ldc + col;
  if (EPI == 0) {
    ((bf16*)C)[off] = (bf16)v;
  } else if (EPI == 1) {
    float z = 0.7978845608f * (v + 0.044715f * v * v * v);
    float gv = v / (1.f + __expf(-2.f * z));   // v*0.5*(1+tanh(z))
    ((bf16*)C)[off] = (bf16)gv;
  } else {
    ((float*)C)[off] = xres[off] + sig * v;
  }
}

#define SYNC256()                                   \
  do {                                              \
    MEMFENCE();                                     \
    __builtin_amdgcn_s_waitcnt(0x0F70);             \
    LGKM0();                                        \
    __builtin_amdgcn_s_barrier();                   \
    MEMFENCE();                                     \
  } while (0)

// ---------------- GEMM 256x256: C[m,n] = sum_k A[m,k] * Bt[n,k] -------------
// BK=64, 8 waves (2M x 4N), per-wave 128x64 (8x4 mfma 16x16x32).
// R6 read-ahead dataflow + SCHED_GROUP_BARRIER fine interleave:
//   region A (P1+P2+P3): 16 ds_reads + 48 MFMA, emitted as 8x{2 DS,4 MFMA} +
//     4x{4 MFMA} so the LDS queue never backlogs behind a read burst (which
//     stalls wave issue and idles the MFMA pipe -- the R4-R6 bottleneck).
//   SYNC: vmcnt(0) [DMA(kt+1), issued ~1.5 tiles earlier -> free] + lgkm +
//     barrier. ONE sync/tile.
//   region B (P4): read (kt+1,k0) frags + DMA(kt+2) [8 gl] + 16 MFMA as
//     4x{2 DS, 2 VMEM, 4 MFMA}.
// Last 2 K-tiles peeled so the main-loop body is branch-free (conditionals
// would split the scheduling region and re-clump the reads).
// LDS swizzle: elem (r,c) at phys col c ^ ((r&7)<<3), applied on the GLOBAL
// source (linear LDS dest) and every ds_read col; XOR wraps the FULL col
// offset incl. the +32 k1 shift.
template <int EPI>
__global__ __launch_bounds__(512, 2) void gemm256(
    const bf16* __restrict__ A, int lda,
    const bf16* __restrict__ Bt, int ldb,
    void* __restrict__ C, int ldc, int NK, int mt, int nt,
    const float* __restrict__ xres, const float* __restrict__ reslog) {
  __shared__ __align__(16) bf16 sA[2 * 16384];   // [dbuf][2 half][128][64] 64KB
  __shared__ __align__(16) bf16 sB[2 * 16384];   // 64KB

  const int tid  = threadIdx.x;
  const int lane = tid & 63;
  const int wave = tid >> 6;
  const int q = lane >> 4, l16 = lane & 15;
  const int wr = wave >> 2, wc = wave & 3;   // 2 x 4 wave grid

  // XCD tile swizzle (nb % 8 == 0, mt % 8 == 0 for all our shapes)
  int nb = mt * nt;
  int per = nb >> 3;
  int t0 = (blockIdx.x & 7) * per + (blockIdx.x >> 3);
  int gsz = nt << 3;
  int g = t0 / gsz, r = t0 % gsz;
  size_t m0 = (size_t)(g * 8 + (r & 7)) * 256;
  size_t n0 = (size_t)(r >> 3) * 256;

  const int srow = tid >> 3;                                   // 0..63
  const int scol = (((tid & 7) ^ ((tid >> 3) & 7)) << 3);
  const bf16* gA = A  + (m0 + srow) * (size_t)lda + scol;
  const bf16* gB = Bt + (n0 + srow) * (size_t)ldb + scol;
  bf16* lA = sA + tid * 8;
  bf16* lB = sB + tid * 8;

  auto stageA = [&](int kt) {          // whole 256x64 A tile (4 gl) -> dbuf kt&1
    const bf16* s = gA + kt * 64;
    bf16* l = lA + (kt & 1) * 16384;
    async16(s, l);
    async16(s + (size_t)64  * lda, l + 4096);
    async16(s + (size_t)128 * lda, l + 8192);
    async16(s + (size_t)192 * lda, l + 12288);
  };
  auto stageB = [&](int kt) {
    const bf16* s = gB + kt * 64;
    bf16* l = lB + (kt & 1) * 16384;
    async16(s, l);
    async16(s + (size_t)64  * ldb, l + 4096);
    async16(s + (size_t)128 * ldb, l + 8192);
    async16(s + (size_t)192 * ldb, l + 12288);
  };

  // prologue: tiles 0 and 1 (16 gl); vmcnt(8) -> tile 0 landed
  stageA(0); stageB(0); stageA(1); stageB(1);
  __builtin_amdgcn_s_waitcnt(0x0F78);
  __builtin_amdgcn_s_barrier();
  MEMFENCE();

  const int sw  = (l16 & 7) << 3;
  const int qx0 = (q << 3) ^ sw;
  const int qx1 = ((q << 3) + 32) ^ sw;
  const bf16* Ard = sA + wr * 8192 + l16 * 64;
  const bf16* Brd = sB + (wc >> 1) * 8192 + ((wc & 1) * 64 + l16) * 64;

  f32x4 acc[8][4] = {};
  bf16x8 a0[4], a1[4], b0[4], b1[4];

  // pre-read: tile0 (m0-3, k0) + b k0
#pragma unroll
  for (int j = 0; j < 4; ++j) a0[j] = *(const bf16x8*)&Ard[j * 1024 + qx0];
#pragma unroll
  for (int n = 0; n < 4; ++n) b0[n] = *(const bf16x8*)&Brd[n * 1024 + qx0];

  // region A: P1 {rd a1(m0-3,k1)+b1(k1) | 16 MFMA a0xb0} P2 {rd a0<-m4-7,k0 |
  // 16 MFMA a1xb1} P3 {rd a1<-m4-7,k1 | 16 MFMA(m4-7) a0xb0} + directives
  auto regA = [&](const bf16* Ab, const bf16* Bb) {
#pragma unroll
    for (int j = 0; j < 4; ++j) a1[j] = *(const bf16x8*)&Ab[j * 1024 + qx1];
#pragma unroll
    for (int n = 0; n < 4; ++n) b1[n] = *(const bf16x8*)&Bb[n * 1024 + qx1];
#pragma unroll
    for (int j = 0; j < 4; ++j)
#pragma unroll
      for (int n = 0; n < 4; ++n)
        acc[j][n] = MFMA16(a0[j], b0[n], acc[j][n]);
#pragma unroll
    for (int j = 0; j < 4; ++j) a0[j] = *(const bf16x8*)&Ab[(4 + j) * 1024 + qx0];
#pragma unroll
    for (int j = 0; j < 4; ++j)
#pragma unroll
      for (int n = 0; n < 4; ++n)
        acc[j][n] = MFMA16(a1[j], b1[n], acc[j][n]);
#pragma unroll
    for (int j = 0; j < 4; ++j) a1[j] = *(const bf16x8*)&Ab[(4 + j) * 1024 + qx1];
#pragma unroll
    for (int j = 0; j < 4; ++j)
#pragma unroll
      for (int n = 0; n < 4; ++n)
        acc[4 + j][n] = MFMA16(a0[j], b0[n], acc[4 + j][n]);
#pragma unroll
    for (int g2 = 0; g2 < 8; ++g2) { SGB(0x100, 2); SGB(0x008, 4); }
#pragma unroll
    for (int g2 = 0; g2 < 4; ++g2) SGB(0x008, 4);
  };

  // region B core: rd a0,b0 <- (kt+1,k0) + 16 MFMA (m4-7) a1xb1
  auto regB = [&](const bf16* Abn, const bf16* Bbn) {
#pragma unroll
    for (int j = 0; j < 4; ++j) a0[j] = *(const bf16x8*)&Abn[j * 1024 + qx0];
#pragma unroll
    for (int n = 0; n < 4; ++n) b0[n] = *(const bf16x8*)&Bbn[n * 1024 + qx0];
#pragma unroll
    for (int j = 0; j < 4; ++j)
#pragma unroll
      for (int n = 0; n < 4; ++n)
        acc[4 + j][n] = MFMA16(a1[j], b1[n], acc[4 + j][n]);
  };

  // main loop (branch-free body): kt in [0, NK-2)
  for (int kt = 0; kt < NK - 2; ++kt) {
    const bf16* Ab  = Ard + (kt & 1) * 16384;
    const bf16* Bb  = Brd + (kt & 1) * 16384;
    const bf16* Abn = Ard + ((kt + 1) & 1) * 16384;
    const bf16* Bbn = Brd + ((kt + 1) & 1) * 16384;

    __builtin_amdgcn_s_setprio(1);
    regA(Ab, Bb);
    __builtin_amdgcn_s_setprio(0);
    SYNC256();
    __builtin_amdgcn_s_setprio(1);
    stageA(kt + 2); stageB(kt + 2);
    regB(Abn, Bbn);
#pragma unroll
    for (int g2 = 0; g2 < 4; ++g2) { SGB(0x100, 2); SGB(0x030, 2); SGB(0x008, 4); }
    __builtin_amdgcn_s_setprio(0);
  }

  // kt = NK-2 (no DMA)
  {
    const int kt = NK - 2;
    const bf16* Ab  = Ard + (kt & 1) * 16384;
    const bf16* Bb  = Brd + (kt & 1) * 16384;
    const bf16* Abn = Ard + ((kt + 1) & 1) * 16384;
    const bf16* Bbn = Brd + ((kt + 1) & 1) * 16384;
    regA(Ab, Bb);
    SYNC256();
    regB(Abn, Bbn);
#pragma unroll
    for (int g2 = 0; g2 < 4; ++g2) { SGB(0x100, 2); SGB(0x008, 4); }
  }
  // kt = NK-1 (no SYNC, no next-tile reads)
  {
    const int kt = NK - 1;
    const bf16* Ab = Ard + (kt & 1) * 16384;
    const bf16* Bb = Brd + (kt & 1) * 16384;
    regA(Ab, Bb);
#pragma unroll
    for (int j = 0; j < 4; ++j)
#pragma unroll
      for (int n = 0; n < 4; ++n)
        acc[4 + j][n] = MFMA16(a1[j], b1[n], acc[4 + j][n]);
  }

  float sig = 0.f;
  if (EPI == 2) sig = 1.f / (1.f + __expf(-reslog[0]));
#pragma unroll
  for (int mi = 0; mi < 8; ++mi)
#pragma unroll
    for (int ni = 0; ni < 4; ++ni) {
      size_t col = n0 + wc * 64 + ni * 16 + l16;
#pragma unroll
      for (int r2 = 0; r2 < 4; ++r2) {
        size_t row = m0 + wr * 128 + mi * 16 + q * 4 + r2;
        epi_store<EPI>(C, ldc, row, col, acc[mi][ni][r2], sig, xres);
      }
    }
}

// ---------------- GEMM 128x256 (wide-grid shapes: Bu, MLP2) -----------------
// 8 waves (2M x 4N), wave-tile 64x64. Same read-ahead + interleave directives.
// region A (P1): 8 reads + 16 MFMA as 4x{2 DS,4 MFMA}. SYNC. region B (P2):
// 8 reads(kt+1,k0) + 6 DMA(kt+2) + 16 MFMA as 3x{2DS,2VMEM,4MFMA}+{2DS,4MFMA}.
// LDS: A 2x16KB + B 2x32KB = 96 KB. Last 2 tiles peeled.
template <int EPI>
__global__ __launch_bounds__(512, 2) void gemm128(
    const bf16* __restrict__ A, int lda,
    const bf16* __restrict__ Bt, int ldb,
    void* __restrict__ C, int ldc, int NK, int mt, int nt,
    const float* __restrict__ xres, const float* __restrict__ reslog) {
  __shared__ __align__(16) bf16 sA[2 * 8192];    // 32 KB
  __shared__ __align__(16) bf16 sB[2 * 16384];   // 64 KB

  const int tid  = threadIdx.x;
  const int lane = tid & 63;
  const int wave = tid >> 6;
  const int q = lane >> 4, l16 = lane & 15;
  const int wr = wave >> 2, wc = wave & 3;

  int nb = mt * nt;
  int per = nb >> 3;
  int t0 = (blockIdx.x & 7) * per + (blockIdx.x >> 3);
  int gsz = nt << 3;
  int g = t0 / gsz, r = t0 % gsz;
  size_t m0 = (size_t)(g * 8 + (r & 7)) * 128;
  size_t n0 = (size_t)(r >> 3) * 256;

  const int srow = tid >> 3;
  const int scol = (((tid & 7) ^ ((tid >> 3) & 7)) << 3);
  const bf16* gA = A  + (m0 + srow) * (size_t)lda + scol;
  const bf16* gB = Bt + (n0 + srow) * (size_t)ldb + scol;
  bf16* lA = sA + tid * 8;
  bf16* lB = sB + tid * 8;

  auto stageA = [&](int kt) {          // 128x64 A tile (2 gl)
    const bf16* s = gA + kt * 64;
    bf16* l = lA + (kt & 1) * 8192;
    async16(s, l);
    async16(s + (size_t)64 * lda, l + 4096);
  };
  auto stageB = [&](int kt) {          // 256x64 B tile (4 gl)
    const bf16* s = gB + kt * 64;
    bf16* l = lB + (kt & 1) * 16384;
    async16(s, l);
    async16(s + (size_t)64  * ldb, l + 4096);
    async16(s + (size_t)128 * ldb, l + 8192);
    async16(s + (size_t)192 * ldb, l + 12288);
  };

  // prologue: tiles 0,1 (12 gl); vmcnt(6) -> tile 0 landed
  stageA(0); stageB(0); stageA(1); stageB(1);
  __builtin_amdgcn_s_waitcnt(0x0F76);
  __builtin_amdgcn_s_barrier();
  MEMFENCE();

  const int sw  = (l16 & 7) << 3;
  const int qx0 = (q << 3) ^ sw;
  const int qx1 = ((q << 3) + 32) ^ sw;
  const bf16* Ard = sA + (wr * 64 + l16) * 64;
  const bf16* Brd = sB + (wc >> 1) * 8192 + ((wc & 1) * 64 + l16) * 64;

  f32x4 acc[4][4] = {};
  bf16x8 a0[4], a1[4], b0[4], b1[4];

  // pre-read tile0 k0
#pragma unroll
  for (int j = 0; j < 4; ++j) a0[j] = *(const bf16x8*)&Ard[j * 1024 + qx0];
#pragma unroll
  for (int n = 0; n < 4; ++n) b0[n] = *(const bf16x8*)&Brd[n * 1024 + qx0];

  auto regA = [&](const bf16* Ab, const bf16* Bb) {
#pragma unroll
    for (int j = 0; j < 4; ++j) a1[j] = *(const bf16x8*)&Ab[j * 1024 + qx1];
#pragma unroll
    for (int n = 0; n < 4; ++n) b1[n] = *(const bf16x8*)&Bb[n * 1024 + qx1];
#pragma unroll
    for (int j = 0; j < 4; ++j)
#pragma unroll
      for (int n = 0; n < 4; ++n)
        acc[j][n] = MFMA16(a0[j], b0[n], acc[j][n]);
#pragma unroll
    for (int g2 = 0; g2 < 4; ++g2) { SGB(0x100, 2); SGB(0x008, 4); }
  };
  auto regB = [&](const bf16* Abn, const bf16* Bbn) {
#pragma unroll
    for (int j = 0; j < 4; ++j) a0[j] = *(const bf16x8*)&Abn[j * 1024 + qx0];
#pragma unroll
    for (int n = 0; n < 4; ++n) b0[n] = *(const bf16x8*)&Bbn[n * 1024 + qx0];
#pragma unroll
    for (int j = 0; j < 4; ++j)
#pragma unroll
      for (int n = 0; n < 4; ++n)
        acc[j][n] = MFMA16(a1[j], b1[n], acc[j][n]);
  };

  for (int kt = 0; kt < NK - 2; ++kt) {
    const bf16* Ab  = Ard + (kt & 1) * 8192;
    const bf16* Bb  = Brd + (kt & 1) * 16384;
    const bf16* Abn = Ard + ((kt + 1) & 1) * 8192;
    const bf16* Bbn = Brd + ((kt + 1) & 1) * 16384;

    __builtin_amdgcn_s_setprio(1);
    regA(Ab, Bb);
    __builtin_amdgcn_s_setprio(0);
    SYNC256();
    __builtin_amdgcn_s_setprio(1);
    stageA(kt + 2); stageB(kt + 2);
    regB(Abn, Bbn);
#pragma unroll
    for (int g2 = 0; g2 < 3; ++g2) { SGB(0x100, 2); SGB(0x030, 2); SGB(0x008, 4); }
    SGB(0x100, 2); SGB(0x008, 4);
    __builtin_amdgcn_s_setprio(0);
  }
  // kt = NK-2 (no DMA)
  {
    const int kt = NK - 2;
    const bf16* Ab  = Ard + (kt & 1) * 8192;
    const bf16* Bb  = Brd + (kt & 1) * 16384;
    const bf16* Abn = Ard + ((kt + 1) & 1) * 8192;
    const bf16* Bbn = Brd + ((kt + 1) & 1) * 16384;
    regA(Ab, Bb);
    SYNC256();
    regB(Abn, Bbn);
#pragma unroll
    for (int g2 = 0; g2 < 4; ++g2) { SGB(0x100, 2); SGB(0x008, 4); }
  }
  // kt = NK-1
  {
    const int kt = NK - 1;
    const bf16* Ab = Ard + (kt & 1) * 8192;
    const bf16* Bb = Brd + (kt & 1) * 16384;
    regA(Ab, Bb);
#pragma unroll
    for (int j = 0; j < 4; ++j)
#pragma unroll
      for (int n = 0; n < 4; ++n)
        acc[j][n] = MFMA16(a1[j], b1[n], acc[j][n]);
  }

  float sig = 0.f;
  if (EPI == 2) sig = 1.f / (1.f + __expf(-reslog[0]));
#pragma unroll
  for (int mi = 0; mi < 4; ++mi)
#pragma unroll
    for (int ni = 0; ni < 4; ++ni) {
      size_t col = n0 + wc * 64 + ni * 16 + l16;
#pragma unroll
      for (int r2 = 0; r2 < 4; ++r2) {
        size_t row = m0 + wr * 64 + mi * 16 + q * 4 + r2;
        epi_store<EPI>(C, ldc, row, col, acc[mi][ni][r2], sig, xres);
      }
    }
}

// ---------------- Scan ----------------
__global__ void scan_pass1(const bf16* __restrict__ Bu, const float* __restrict__ scal,
                           float2* __restrict__ H) {
  int b = blockIdx.x >> 6, c = blockIdx.x & 63, n = threadIdx.x;
  float lr = scal[n], li = scal[256 + n];
  float sr = 0.f, si = 0.f;
  size_t t0 = (size_t)b * L_ + (size_t)c * CL;
  const uint32_t* p = (const uint32_t*)(Bu + t0 * 512) + n;
  for (int j = 0; j < CL; j++) {
    uint32_t u = p[(size_t)j * 256];
    float ur = bfbits(u & 0xffffu), ui = bfbits(u >> 16);
    float nr = lr * sr - li * si + ur;
    float ni = lr * si + li * sr + ui;
    sr = nr; si = ni;
  }
  H[(size_t)(b * NC + c) * 256 + n] = make_float2(sr, si);
}

__global__ void scan_pass2(const float2* __restrict__ H, const float* __restrict__ scal,
                           float2* __restrict__ Carry) {
  int b = blockIdx.x, n = threadIdx.x;
  float Pr = scal[512 + n], Pi = scal[768 + n];
  float cr = 0.f, ci = 0.f;
  for (int c = 0; c < NC; c++) {
    Carry[(size_t)(b * NC + c) * 256 + n] = make_float2(cr, ci);
    float2 h = H[(size_t)(b * NC + c) * 256 + n];
    float nr = Pr * cr - Pi * ci + h.x;
    float ni = Pr * ci + Pi * cr + h.y;
    cr = nr; ci = ni;
  }
}

// st layout: PLANAR-GLOBAL — st[0..1023] = re (b-major), st[1024..2047] = im
__global__ void scan_pass3(const bf16* __restrict__ Bu, const float* __restrict__ scal,
                           const float2* __restrict__ Carry, bf16* __restrict__ XS,
                           float* __restrict__ st) {
  int b = blockIdx.x >> 6, c = blockIdx.x & 63, n = threadIdx.x;
  float lr = scal[n], li = scal[256 + n];
  float2 cv = Carry[(size_t)(b * NC + c) * 256 + n];
  float sr = cv.x, si = cv.y;
  size_t t0 = (size_t)b * L_ + (size_t)c * CL;
  const uint32_t* p = (const uint32_t*)(Bu + t0 * 512) + n;
  bf16* qp = XS + t0 * 1536 + n;
  for (int j = 0; j < CL; j++) {
    uint32_t u = p[(size_t)j * 256];
    float ur = bfbits(u & 0xffffu), ui = bfbits(u >> 16);
    float nr = lr * sr - li * si + ur;
    float ni = lr * si + li * sr + ui;
    sr = nr; si = ni;
    qp[(size_t)j * 1536] = (bf16)sr;
    qp[(size_t)j * 1536 + 256] = (bf16)si;
  }
  if (c == NC - 1) {
    st[(size_t)b * 256 + n] = sr;
    st[1024 + (size_t)b * 256 + n] = si;
  }
}

// ---------------- Launch ----------------
extern "C" void kernel_launch(void* const* d_in, const int* in_sizes, int n_in,
                              void* d_out, int out_size, void* d_ws, size_t ws_size,
                              hipStream_t stream) {
  const float* x      = (const float*)d_in[0];
  const float* nu_log = (const float*)d_in[1];
  const float* th_log = (const float*)d_in[2];
  const float* B_re   = (const float*)d_in[3];
  const float* B_im   = (const float*)d_in[4];
  const float* C_re   = (const float*)d_in[5];
  const float* C_im   = (const float*)d_in[6];
  const float* D_mat  = (const float*)d_in[7];
  const float* W1     = (const float*)d_in[8];
  const float* W2     = (const float*)d_in[9];
  const float* reslog = (const float*)d_in[10];

  char* wsb = (char*)d_ws;
  size_t off = 0;
  auto alloc = [&](size_t bytes) {
    void* p = wsb + off;
    off += (bytes + 255) & ~(size_t)255;
    return p;
  };
  float*  scal = (float*)alloc(5 * 256 * 4);
  bf16*   WBbu = (bf16*)alloc((size_t)512 * 1024 * 2);
  bf16*   WBy  = (bf16*)alloc((size_t)1024 * 1536 * 2);
  bf16*   WB1  = (bf16*)alloc((size_t)4096 * 1024 * 2);   // W1^T
  bf16*   WB2  = (bf16*)alloc((size_t)1024 * 4096 * 2);   // W2^T
  float2* H    = (float2*)alloc((size_t)B_ * NC * 256 * 8);
  float2* Cr   = (float2*)alloc((size_t)B_ * NC * 256 * 8);
  bf16*   Ybf  = (bf16*)alloc((size_t)BL * 1024 * 2);
  bf16*   XS   = (bf16*)alloc((size_t)BL * 1536 * 2);     // [Sr|Si|x]
  bf16*   Bu   = (bf16*)alloc((size_t)BL * 512 * 2);
  // gelu buffer (8192x4096 bf16 = 64 MB) aliases XS+Bu (dead by MLP time)
  bf16*   Hbf  = XS;

  float* out = (float*)d_out;
  float* st  = out + (size_t)BL * DM;

  // fused prep: conv_x(16384) | prep_y(6144) | prep_bu(2048) | W1^T(4096) |
  // W2^T(4096) | phaseA(1)  => 32769 blocks
  prep_fused<<<32769, 256, 0, stream>>>(
      (const float4*)x, XS, C_re, C_im, D_mat, WBy,
      B_re, B_im, nu_log, th_log, WBbu, W1, WB1, W2, WB2, scal);

  // Bu = x @ [gammaB]^T  (M=16384, N=512, K=1024): 128x256 tiles -> 256 blocks
  gemm128<0><<<128 * 2, 512, 0, stream>>>(
      XS + 512, 1536, WBbu, 1024, Bu, 512, 16, 128, 2, nullptr, nullptr);

  scan_pass1<<<B_ * NC, 256, 0, stream>>>(Bu, scal, H);
  scan_pass2<<<B_, 256, 0, stream>>>(H, scal, Cr);
  scan_pass3<<<B_ * NC, 256, 0, stream>>>(Bu, scal, Cr, XS, st);

  // y = [Sr|Si|x] @ [C_re|-C_im|D]^T  (M=16384, N=1024, K=1536): 256^2, 256 blk
  gemm256<0><<<64 * 4, 512, 0, stream>>>(
      XS, 1536, WBy, 1536, Ybf, 1024, 24, 64, 4, nullptr, nullptr);

  // MLP, M-chunked by 8192 rows (2 chunks)
  for (int i = 0; i < 2; i++) {
    const bf16* Yc = Ybf + (size_t)i * 8192 * 1024;
    float* Oc = out + (size_t)i * 8192 * 1024;
    const float* Xc = x + (size_t)i * 8192 * 1024;
    // MLP1: M=8192, N=4096, K=1024 -> 256^2, 512 blocks (2 rounds)
    gemm256<1><<<32 * 16, 512, 0, stream>>>(
        Yc, 1024, WB1, 1024, Hbf, 4096, 16, 32, 16, nullptr, nullptr);
    // MLP2: M=8192, N=1024, K=4096 -> 128x256 tiles, 256 blocks (full GPU)
    gemm128<2><<<64 * 4, 512, 0, stream>>>(
        Hbf, 4096, WB2, 4096, Oc, 1024, 64, 64, 4, Xc, reslog);
  }
}